// Round 19
// baseline (159.885 us; speedup 1.0000x reference)
//
#include <hip/hip_runtime.h>

// ---------------------------------------------------------------------------
// Fused attention block: qkv-proj(+RoPE fused) -> flash attention -> out-proj
// B=8 N=1024 C=1024 H=16 D=64.  All matmuls bf16 MFMA 16x16x32, fp32 acc.
// R19: GEMM = R13 geometry (64x64 waves, ratio-law optimal) + R15 3-buffer
// counted-vmcnt pipeline (removes the barrier drain that killed R13's 2-wave
// occupancy).  prep vectorized via v_cvt_pk_bf16_f32 grid-stride.
// ---------------------------------------------------------------------------

typedef __attribute__((ext_vector_type(8))) short bf16x8;
typedef __attribute__((ext_vector_type(4))) float floatx4;
typedef __attribute__((ext_vector_type(4))) unsigned int u32x4;
typedef __attribute__((ext_vector_type(2))) unsigned int u32x2;

__device__ __forceinline__ void gld16(const void* g, void* l) {
  __builtin_amdgcn_global_load_lds((const __attribute__((address_space(1))) void*)g,
                                   (__attribute__((address_space(3))) void*)l, 16, 0, 0);
}

__device__ __forceinline__ short f2bf(float f) {          // RNE fp32->bf16
  unsigned u = __builtin_bit_cast(unsigned, f);
  u = (u + 0x7FFFu + ((u >> 16) & 1u)) >> 16;
  return (short)u;
}
__device__ __forceinline__ unsigned cvtpk(float lo, float hi) {
  unsigned r;
  asm("v_cvt_pk_bf16_f32 %0, %1, %2" : "=v"(r) : "v"(lo), "v"(hi));
  return r;
}
__device__ __forceinline__ float pexp(float x) {          // raw v_exp_f32 (2^x)
  float r;
  asm("v_exp_f32 %0, %1" : "=v"(r) : "v"(x));
  return r;
}

// ---------------- prep: fp32->bf16 (x|qkv_w|proj_w) + RoPE cos/sin table ----------------
// blocks 0..2047: grid-stride cvt over 3145728 float4 (cvtpk packing).
// blocks 2048..2303: RoPE table.
__global__ __launch_bounds__(256) void prep_all(const float* __restrict__ sx,
                                                const float* __restrict__ sq,
                                                const float* __restrict__ sp,
                                                short* __restrict__ dst,
                                                const float* __restrict__ ropef,
                                                float2* __restrict__ tbl) {
  int bid = blockIdx.x;
  if (bid < 2048) {
    for (int i = bid * 256 + threadIdx.x; i < 3145728; i += 2048 * 256) {
      const float4* src;
      if (i < 2097152)      src = reinterpret_cast<const float4*>(sx) + i;
      else if (i < 2883584) src = reinterpret_cast<const float4*>(sq) + (i - 2097152);
      else                  src = reinterpret_cast<const float4*>(sp) + (i - 2883584);
      float4 v = *src;
      uint2 o;
      o.x = cvtpk(v.x, v.y);
      o.y = cvtpk(v.z, v.w);
      reinterpret_cast<uint2*>(dst)[i] = o;
    }
  } else {
    int i = (bid - 2048) * 256 + threadIdx.x;   // 0 .. 65535
    float v = ropef[i];
    tbl[i] = make_float2(cosf(v), sinf(v));
  }
}

// scale (D^-0.5 = 1/8) * log2(e): softmax computed with exp2
#define QSCALE 0.18033688011112042f

// ---------------- GEMM core: C[128x256] = A[128xK] * B[256xK]^T, K=1024 ----------------
// R19: BM=128 BN=256 BK=64, 512 thr / 8 waves (2Mx4N; per-wave 64x64, acc[4][4]) --
// the LDS-ratio-optimal geometry -- with the R15 TRIPLE-buffer counted-vmcnt pipeline:
// iter t issues stage(t+2) (6 loads/thread); end-of-iter s_waitcnt vmcnt(6) retires
// tile t+1's loads while t+2's stay in flight (no vmcnt(0) drain mid-loop).
// LDS (dynamic 144 KB): As[3][128*64] @ 0, Bs[3][256*64] @ 24576 (shorts).
__device__ __forceinline__ void gemm_main(const short* __restrict__ A,
                                          const short* __restrict__ Bm,
                                          short* As, short* Bs,
                                          floatx4 (&acc)[4][4],
                                          int bx, int by) {
  const int tid = threadIdx.x;
  const int wid = tid >> 6, lane = tid & 63;
  const int g = lane >> 4, l15 = lane & 15;
  const int wr = wid >> 2, wc = wid & 3;          // 2 row-bands(64) x 4 col-bands(64)
  const size_t trow = (size_t)by * 128, tcol = (size_t)bx * 256;
  floatx4 zero = {0.f, 0.f, 0.f, 0.f};
  #pragma unroll
  for (int i = 0; i < 4; ++i)
    #pragma unroll
    for (int j = 0; j < 4; ++j) acc[i][j] = zero;

  auto stage = [&](int buf, int k0) {
    #pragma unroll
    for (int i = 0; i < 2; ++i) {
      const int cb = (i * 8 + wid) * 64;      // A: 1024 chunks of 16B
      const int c  = cb + lane;
      const int r  = c >> 3, s = c & 7;
      const int koff = k0 + ((s ^ (r & 7)) << 3);
      gld16(A + (trow + r) * 1024 + koff, As + buf * 8192 + (size_t)cb * 8);
    }
    #pragma unroll
    for (int i = 0; i < 4; ++i) {
      const int cb = (i * 8 + wid) * 64;      // B: 2048 chunks of 16B
      const int c  = cb + lane;
      const int r  = c >> 3, s = c & 7;
      const int koff = k0 + ((s ^ (r & 7)) << 3);
      gld16(Bm + (tcol + r) * 1024 + koff, Bs + buf * 16384 + (size_t)cb * 8);
    }
  };

  // prologue: tiles 0,1 staged; retire tile 0's loads only (tile 1 in flight)
  stage(0, 0);
  stage(1, 64);
  asm volatile("s_waitcnt vmcnt(6)" ::: "memory");
  __builtin_amdgcn_s_barrier();
  asm volatile("" ::: "memory");

  int btop = 0;
  for (int t = 0; t < 16; ++t) {
    if (t < 14) {
      int bnx = btop + 2; if (bnx >= 3) bnx -= 3;
      stage(bnx, (t + 2) * 64);               // loads span 2 compute phases
    }
    const short* Ab = As + btop * 8192;
    const short* Bb = Bs + btop * 16384;
    #pragma unroll
    for (int ks = 0; ks < 2; ++ks) {
      bf16x8 af[4], bfr[4];
      #pragma unroll
      for (int mi = 0; mi < 4; ++mi) {
        int row = wr * 64 + mi * 16 + l15;
        int ch  = (ks * 4 + g) ^ (row & 7);
        af[mi] = *reinterpret_cast<const bf16x8*>(Ab + row * 64 + ch * 8);
      }
      #pragma unroll
      for (int nt = 0; nt < 4; ++nt) {
        int row = wc * 64 + nt * 16 + l15;
        int ch  = (ks * 4 + g) ^ (row & 7);
        bfr[nt] = *reinterpret_cast<const bf16x8*>(Bb + row * 64 + ch * 8);
      }
      __builtin_amdgcn_s_setprio(1);
      #pragma unroll
      for (int mi = 0; mi < 4; ++mi)
        #pragma unroll
        for (int nt = 0; nt < 4; ++nt)
          acc[mi][nt] = __builtin_amdgcn_mfma_f32_16x16x32_bf16(af[mi], bfr[nt],
                                                                acc[mi][nt], 0, 0, 0);
      __builtin_amdgcn_s_setprio(0);
    }
    // counted-vmcnt barrier: retire tile t+1's loads, keep t+2's in flight
    if (t < 15) {
      if (t < 14) asm volatile("s_waitcnt vmcnt(6)" ::: "memory");
      else        asm volatile("s_waitcnt vmcnt(0)" ::: "memory");
      __builtin_amdgcn_s_barrier();
      asm volatile("" ::: "memory");
    }
    btop = btop + 1 == 3 ? 0 : btop + 1;
  }
}

// QKV GEMM with fused RoPE epilogue.  bx: 0..3 -> q, 4..7 -> k, 8..11 -> v.
// q/k written [bh][n][d] with RoPE (q also pre-scaled); v written TRANSPOSED [bh][d][n].
__global__ __launch_bounds__(512) void gemm_qkv_k(const short* __restrict__ A,
                                                  const short* __restrict__ Bm,
                                                  const float2* __restrict__ tbl,
                                                  short* __restrict__ qo,
                                                  short* __restrict__ ko,
                                                  short* __restrict__ vt) {
  extern __shared__ __align__(16) short smem[];
  short* As = smem;             // 3 x 128*64
  short* Bs = smem + 24576;     // 3 x 256*64
  // XCD-aware bijective swizzle: nwg = 12*64 = 768, 768 % 8 == 0.
  const int id  = blockIdx.y * 12 + blockIdx.x;
  const int sid = (id & 7) * 96 + (id >> 3);
  const int bx  = sid % 12, by = sid / 12;
  floatx4 acc[4][4];
  gemm_main(A, Bm, As, Bs, acc, bx, by);

  const int tid = threadIdx.x;
  const int wid = tid >> 6, lane = tid & 63;
  const int g = lane >> 4, l15 = lane & 15;
  const int wr = wid >> 2, wc = wid & 3;
  const int trow = by * 128, tcol = bx * 256;
  const int which = bx >> 2;

  if (which < 2) {
    short* dst = which == 0 ? qo : ko;
    const float sc = which == 0 ? QSCALE : 1.0f;
    #pragma unroll
    for (int nt = 0; nt < 2; ++nt) {              // pairs (nt, nt+2) = (d, d+32)
      int col = tcol + wc * 64 + nt * 16 + l15;
      int hc = col & 1023, h = hc >> 6, d1 = hc & 63;   // d1 in [0,32)
      #pragma unroll
      for (int mi = 0; mi < 4; ++mi)
        #pragma unroll
        for (int r = 0; r < 4; ++r) {
          int rowg = trow + wr * 64 + mi * 16 + g * 4 + r;
          int b = rowg >> 10, n = rowg & 1023;
          float a1 = acc[mi][nt][r], a2 = acc[mi][nt + 2][r];
          float2 c1 = tbl[n * 64 + d1];
          float2 c2 = tbl[n * 64 + d1 + 32];
          float o1 = (a1 * c1.x - a2 * c1.y) * sc;
          float o2 = (a2 * c2.x + a1 * c2.y) * sc;
          size_t base = ((size_t)(b * 16 + h) * 1024 + n) * 64;
          dst[base + d1]      = f2bf(o1);
          dst[base + d1 + 32] = f2bf(o2);
        }
    }
  } else {
    // V^T [bh][d=64][n=1024]; acc reg axis r = consecutive n -> 8B packed stores
    #pragma unroll
    for (int nt = 0; nt < 4; ++nt) {
      int col = tcol + wc * 64 + nt * 16 + l15;
      int hc = col & 1023, h = hc >> 6, d = hc & 63;
      #pragma unroll
      for (int mi = 0; mi < 4; ++mi) {
        int rowg = trow + wr * 64 + mi * 16 + g * 4;
        int b = rowg >> 10, n0 = rowg & 1023;
        ushort4 pk;
        pk.x = (unsigned short)f2bf(acc[mi][nt][0]);
        pk.y = (unsigned short)f2bf(acc[mi][nt][1]);
        pk.z = (unsigned short)f2bf(acc[mi][nt][2]);
        pk.w = (unsigned short)f2bf(acc[mi][nt][3]);
        *reinterpret_cast<ushort4*>((unsigned short*)vt +
            ((size_t)(b * 16 + h) * 64 + d) * 1024 + n0) = pk;
      }
    }
  }
}

// Proj GEMM: attn_out bf16 [8192x1024] x proj_w bf16 [1024x1024]^T + bias -> fp32
__global__ __launch_bounds__(512) void gemm_proj_k(const short* __restrict__ A,
                                                   const short* __restrict__ Bm,
                                                   const float* __restrict__ pb,
                                                   float* __restrict__ out) {
  extern __shared__ __align__(16) short smem[];
  short* As = smem;             // 3 x 128*64
  short* Bs = smem + 24576;     // 3 x 256*64
  // XCD-aware bijective swizzle: nwg = 4*64 = 256, 256 % 8 == 0.
  const int id  = blockIdx.y * 4 + blockIdx.x;
  const int sid = (id & 7) * 32 + (id >> 3);
  const int bx  = sid % 4, by = sid / 4;
  floatx4 acc[4][4];
  gemm_main(A, Bm, As, Bs, acc, bx, by);

  const int tid = threadIdx.x;
  const int wid = tid >> 6, lane = tid & 63;
  const int g = lane >> 4, l15 = lane & 15;
  const int wr = wid >> 2, wc = wid & 3;
  const int trow = by * 128, tcol = bx * 256;
  #pragma unroll
  for (int nt = 0; nt < 4; ++nt) {
    int col = tcol + wc * 64 + nt * 16 + l15;
    float bias = pb[col];
    #pragma unroll
    for (int mi = 0; mi < 4; ++mi)
      #pragma unroll
      for (int r = 0; r < 4; ++r) {
        int rowg = trow + wr * 64 + mi * 16 + g * 4 + r;
        out[(size_t)rowg * 1024 + col] = acc[mi][nt][r] + bias;
      }
  }
}

// ---------------- flash attention (swapped-QK^T, no-max softmax, 256-q blocks) --------
// R18 version (verified): grid (128 bh, 4 q-tiles of 256); FOUR 64-q halves share each
// K/V tile's ds_reads; two k=32 slices bound VGPR; 3-buf counted-vmcnt staging.
__global__ __launch_bounds__(256) void attn_kernel(const short* __restrict__ qs,
                                                   const short* __restrict__ ksrc,
                                                   const short* __restrict__ vt,
                                                   short* __restrict__ aout) {
  __shared__ __align__(16) short Kl[3][64 * 64];
  __shared__ __align__(16) short Vl[3][64 * 64];

  const int tid = threadIdx.x, wid = tid >> 6, lane = tid & 63;
  const int g = lane >> 4, l15 = lane & 15;
  const int bh = blockIdx.x, q0 = blockIdx.y * 256;
  const size_t bhoff = (size_t)bh * 1024 * 64;
  const short* Kb = ksrc + bhoff;          // [n][d]
  const short* Vb = vt + bhoff;            // [d][n]
  const int slb = (lane & 48) + ((lane >> 4) << 2);

  const short* QpA = qs + bhoff + (size_t)(q0 + wid * 16 + l15) * 64 + g * 8;
  bf16x8 qA0 = *reinterpret_cast<const bf16x8*>(QpA);
  bf16x8 qA1 = *reinterpret_cast<const bf16x8*>(QpA + 32);
  bf16x8 qB0 = *reinterpret_cast<const bf16x8*>(QpA + 64 * 64);
  bf16x8 qB1 = *reinterpret_cast<const bf16x8*>(QpA + 64 * 64 + 32);
  bf16x8 qC0 = *reinterpret_cast<const bf16x8*>(QpA + 128 * 64);
  bf16x8 qC1 = *reinterpret_cast<const bf16x8*>(QpA + 128 * 64 + 32);
  bf16x8 qD0 = *reinterpret_cast<const bf16x8*>(QpA + 192 * 64);
  bf16x8 qD1 = *reinterpret_cast<const bf16x8*>(QpA + 192 * 64 + 32);

  floatx4 oA[4], oB[4], oC[4], oD[4];
  floatx4 zero = {0.f, 0.f, 0.f, 0.f};
  #pragma unroll
  for (int i = 0; i < 4; ++i) { oA[i] = zero; oB[i] = zero; oC[i] = zero; oD[i] = zero; }
  float lrunA = 0.f, lrunB = 0.f, lrunC = 0.f, lrunD = 0.f;

  auto stage = [&](int buf, int t) {
    #pragma unroll
    for (int i = 0; i < 2; ++i) {
      const int cb = (i * 4 + wid) * 64;         // wave-uniform chunk base
      const int c = cb + lane;
      const int r = c >> 3, s = c & 7;
      const int off = (s ^ (r & 7)) << 3;        // pre-swizzled source
      gld16(Kb + (size_t)(t * 64 + r) * 64 + off, &Kl[buf][cb * 8]);
      gld16(Vb + (size_t)r * 1024 + t * 64 + off, &Vl[buf][cb * 8]);
    }
  };

#define SOFTSLICE(s_, lrun, pa)                                                \
  do {                                                                         \
    float p0 = pexp(s_[0][0]), p1 = pexp(s_[0][1]);                            \
    float p2 = pexp(s_[0][2]), p3 = pexp(s_[0][3]);                            \
    float p4 = pexp(s_[1][0]), p5 = pexp(s_[1][1]);                            \
    float p6 = pexp(s_[1][2]), p7 = pexp(s_[1][3]);                            \
    lrun += ((p0 + p1) + (p2 + p3)) + ((p4 + p5) + (p6 + p7));                 \
    unsigned wa0 = cvtpk(p0, p1), wa1 = cvtpk(p2, p3);                         \
    unsigned wb0 = cvtpk(p4, p5), wb1 = cvtpk(p6, p7);                         \
    u32x2 y0 = __builtin_amdgcn_permlane32_swap(wa0, wb0, false, false);       \
    u32x2 z0 = __builtin_amdgcn_permlane16_swap(y0[0], y0[1], false, false);   \
    u32x2 y1 = __builtin_amdgcn_permlane32_swap(wa1, wb1, false, false);       \
    u32x2 z1 = __builtin_amdgcn_permlane16_swap(y1[0], y1[1], false, false);   \
    u32x4 aw = {z0[0], z1[0], z0[1], z1[1]};                                   \
    pa = __builtin_bit_cast(bf16x8, aw);                                       \
  } while (0)

#define QKSLICE(base, sA_, sB_, sC_, sD_)                                      \
  __builtin_amdgcn_s_setprio(1);                                               \
  _Pragma("unroll")                                                            \
  for (int kk = 0; kk < 2; ++kk) {                                             \
    int krow = (base + kk) * 16 + l15;                                         \
    int ch0 = (g ^ (krow & 7)) << 3, ch1 = ((4 + g) ^ (krow & 7)) << 3;        \
    bf16x8 kf0 = *reinterpret_cast<const bf16x8*>(&Kl[btop][krow * 64 + ch0]); \
    sA_[kk] = __builtin_amdgcn_mfma_f32_16x16x32_bf16(kf0, qA0, sA_[kk],0,0,0);\
    sB_[kk] = __builtin_amdgcn_mfma_f32_16x16x32_bf16(kf0, qB0, sB_[kk],0,0,0);\
    sC_[kk] = __builtin_amdgcn_mfma_f32_16x16x32_bf16(kf0, qC0, sC_[kk],0,0,0);\
    sD_[kk] = __builtin_amdgcn_mfma_f32_16x16x32_bf16(kf0, qD0, sD_[kk],0,0,0);\
    bf16x8 kf1 = *reinterpret_cast<const bf16x8*>(&Kl[btop][krow * 64 + ch1]); \
    sA_[kk] = __builtin_amdgcn_mfma_f32_16x16x32_bf16(kf1, qA1, sA_[kk],0,0,0);\
    sB_[kk] = __builtin_amdgcn_mfma_f32_16x16x32_bf16(kf1, qB1, sB_[kk],0,0,0);\
    sC_[kk] = __builtin_amdgcn_mfma_f32_16x16x32_bf16(kf1, qC1, sC_[kk],0,0,0);\
    sD_[kk] = __builtin_amdgcn_mfma_f32_16x16x32_bf16(kf1, qD1, sD_[kk],0,0,0);\
  }                                                                            \
  __builtin_amdgcn_s_setprio(0);

#define PVSLICE(chsel, paA_, paB_, paC_, paD_)                                 \
  __builtin_amdgcn_s_setprio(1);                                               \
  _Pragma("unroll")                                                            \
  for (int nt = 0; nt < 4; ++nt) {                                             \
    int row = nt * 16 + l15;                                                   \
    int ch = (((chsel) + g) ^ (row & 7)) << 3;                                 \
    bf16x8 vf = *reinterpret_cast<const bf16x8*>(&Vl[btop][row * 64 + ch]);    \
    oA[nt] = __builtin_amdgcn_mfma_f32_16x16x32_bf16(paA_, vf, oA[nt],0,0,0);  \
    oB[nt] = __builtin_amdgcn_mfma_f32_16x16x32_bf16(paB_, vf, oB[nt],0,0,0);  \
    oC[nt] = __builtin_amdgcn_mfma_f32_16x16x32_bf16(paC_, vf, oC[nt],0,0,0);  \
    oD[nt] = __builtin_amdgcn_mfma_f32_16x16x32_bf16(paD_, vf, oD[nt],0,0,0);  \
  }                                                                            \
  __builtin_amdgcn_s_setprio(0);

  stage(0, 0);
  stage(1, 1);
  asm volatile("s_waitcnt vmcnt(4)" ::: "memory");
  __builtin_amdgcn_s_barrier();
  asm volatile("" ::: "memory");

  int btop = 0;
  for (int t = 0; t < 16; ++t) {
    if (t < 14) {
      int bnx = btop + 2; if (bnx >= 3) bnx -= 3;
      stage(bnx, t + 2);                       // loads span 2 compute phases
    }

    {  // slice 0: k = 0..31
      floatx4 sA[2], sB[2], sC[2], sD[2];
      #pragma unroll
      for (int kk = 0; kk < 2; ++kk) { sA[kk]=zero; sB[kk]=zero; sC[kk]=zero; sD[kk]=zero; }
      QKSLICE(0, sA, sB, sC, sD);
      bf16x8 paA, paB, paC, paD;
      SOFTSLICE(sA, lrunA, paA);
      SOFTSLICE(sB, lrunB, paB);
      SOFTSLICE(sC, lrunC, paC);
      SOFTSLICE(sD, lrunD, paD);
      PVSLICE(0, paA, paB, paC, paD);
    }
    {  // slice 1: k = 32..63
      floatx4 sA[2], sB[2], sC[2], sD[2];
      #pragma unroll
      for (int kk = 0; kk < 2; ++kk) { sA[kk]=zero; sB[kk]=zero; sC[kk]=zero; sD[kk]=zero; }
      QKSLICE(2, sA, sB, sC, sD);
      bf16x8 paA, paB, paC, paD;
      SOFTSLICE(sA, lrunA, paA);
      SOFTSLICE(sB, lrunB, paB);
      SOFTSLICE(sC, lrunC, paC);
      SOFTSLICE(sD, lrunD, paD);
      PVSLICE(4, paA, paB, paC, paD);
    }

    if (t < 15) {
      if (t < 14) asm volatile("s_waitcnt vmcnt(4)" ::: "memory");
      else        asm volatile("s_waitcnt vmcnt(0)" ::: "memory");
      __builtin_amdgcn_s_barrier();
      asm volatile("" ::: "memory");
    }
    btop = btop + 1 == 3 ? 0 : btop + 1;
  }

  // ---- epilogue ----
  const int b = bh >> 4, h = bh & 15;
  lrunA += __shfl_xor(lrunA, 16); lrunA += __shfl_xor(lrunA, 32);
  lrunB += __shfl_xor(lrunB, 16); lrunB += __shfl_xor(lrunB, 32);
  lrunC += __shfl_xor(lrunC, 16); lrunC += __shfl_xor(lrunC, 32);
  lrunD += __shfl_xor(lrunD, 16); lrunD += __shfl_xor(lrunD, 32);
  float invA = 1.f / lrunA, invB = 1.f / lrunB;
  float invC = 1.f / lrunC, invD = 1.f / lrunD;
  #pragma unroll
  for (int r = 0; r < 4; ++r) {
    float irA = __shfl(invA, slb + r);
    float irB = __shfl(invB, slb + r);
    float irC = __shfl(invC, slb + r);
    float irD = __shfl(invD, slb + r);
    int nA = q0 + wid * 16 + g * 4 + r;
    size_t baseA = ((size_t)(b * 1024) + nA) * 1024 + h * 64;
    size_t baseB = baseA + (size_t)64 * 1024;
    size_t baseC = baseA + (size_t)128 * 1024;
    size_t baseD = baseA + (size_t)192 * 1024;
    #pragma unroll
    for (int nt = 0; nt < 4; ++nt) {
      aout[baseA + nt * 16 + l15] = f2bf(oA[nt][r] * irA);
      aout[baseB + nt * 16 + l15] = f2bf(oB[nt][r] * irB);
      aout[baseC + nt * 16 + l15] = f2bf(oC[nt][r] * irC);
      aout[baseD + nt * 16 + l15] = f2bf(oD[nt][r] * irD);
    }
  }
#undef SOFTSLICE
#undef QKSLICE
#undef PVSLICE
}

// ---------------------------------------------------------------------------
extern "C" void kernel_launch(void* const* d_in, const int* in_sizes, int n_in,
                              void* d_out, int out_size, void* d_ws, size_t ws_size,
                              hipStream_t stream) {
  const float* x      = (const float*)d_in[0];   // [8,1024,1024]
  const float* ropef  = (const float*)d_in[1];   // [1,1024,1,64]
  const float* qkv_w  = (const float*)d_in[2];   // [3072,1024]
  const float* proj_w = (const float*)d_in[3];   // [1024,1024]
  const float* proj_b = (const float*)d_in[4];   // [1024]
  float* out = (float*)d_out;

  char* ws = (char*)d_ws;
  short*  xb  = (short*)(ws + 0);            // 16 MB  x bf16        (contiguous with)
  short*  wqb = (short*)(ws + 16777216);     //  6 MB  qkv_w bf16    (contiguous with)
  short*  wpb = (short*)(ws + 23068672);     //  2 MB  proj_w bf16
  short*  qb  = (short*)(ws + 25165824);     // 16 MB  q [bh][n][d] (RoPE+scale)
  short*  kb  = (short*)(ws + 41943040);     // 16 MB  k [bh][n][d] (RoPE)
  short*  vtb = (short*)(ws + 58720256);     // 16 MB  v^T [bh][d][n]
  short*  aob = (short*)(ws + 75497472);     // 16 MB  attn out bf16 [B][N][C]
  float2* tbl = (float2*)(ws + 92274688);    // 512 KB cos/sin table

  prep_all<<<2304, 256, 0, stream>>>(x, qkv_w, proj_w, xb, ropef, tbl);

  gemm_qkv_k<<<dim3(12, 64), 512, 147456, stream>>>(xb, wqb, tbl, qb, kb, vtb);
  attn_kernel<<<dim3(128, 4), 256, 0, stream>>>(qb, kb, vtb, aob);
  gemm_proj_k<<<dim3(4, 64), 512, 147456, stream>>>(aob, wpb, proj_b, out);
}

// Round 20
// 155.683 us; speedup vs baseline: 1.0270x; 1.0270x over previous
//
#include <hip/hip_runtime.h>

// ---------------------------------------------------------------------------
// Fused attention block: qkv-proj(+RoPE fused) -> flash attention -> out-proj
// B=8 N=1024 C=1024 H=16 D=64.  All matmuls bf16 MFMA 16x16x32, fp32 acc.
// R20 consolidation: R12 GEMM (occupancy-optimal 16-wave 128x256; R13/R16/R19
// all lost to it) + R18 attn (4-half shared-ds_read) + R19 grid-stride cvtpk prep.
// ---------------------------------------------------------------------------

typedef __attribute__((ext_vector_type(8))) short bf16x8;
typedef __attribute__((ext_vector_type(4))) float floatx4;
typedef __attribute__((ext_vector_type(4))) unsigned int u32x4;
typedef __attribute__((ext_vector_type(2))) unsigned int u32x2;

__device__ __forceinline__ void gld16(const void* g, void* l) {
  __builtin_amdgcn_global_load_lds((const __attribute__((address_space(1))) void*)g,
                                   (__attribute__((address_space(3))) void*)l, 16, 0, 0);
}

__device__ __forceinline__ short f2bf(float f) {          // RNE fp32->bf16
  unsigned u = __builtin_bit_cast(unsigned, f);
  u = (u + 0x7FFFu + ((u >> 16) & 1u)) >> 16;
  return (short)u;
}
__device__ __forceinline__ unsigned cvtpk(float lo, float hi) {
  unsigned r;
  asm("v_cvt_pk_bf16_f32 %0, %1, %2" : "=v"(r) : "v"(lo), "v"(hi));
  return r;
}
__device__ __forceinline__ float pexp(float x) {          // raw v_exp_f32 (2^x)
  float r;
  asm("v_exp_f32 %0, %1" : "=v"(r) : "v"(x));
  return r;
}

// ---------------- prep: fp32->bf16 (x|qkv_w|proj_w) + RoPE cos/sin table ----------------
__global__ __launch_bounds__(256) void prep_all(const float* __restrict__ sx,
                                                const float* __restrict__ sq,
                                                const float* __restrict__ sp,
                                                short* __restrict__ dst,
                                                const float* __restrict__ ropef,
                                                float2* __restrict__ tbl) {
  int bid = blockIdx.x;
  if (bid < 2048) {
    for (int i = bid * 256 + threadIdx.x; i < 3145728; i += 2048 * 256) {
      const float4* src;
      if (i < 2097152)      src = reinterpret_cast<const float4*>(sx) + i;
      else if (i < 2883584) src = reinterpret_cast<const float4*>(sq) + (i - 2097152);
      else                  src = reinterpret_cast<const float4*>(sp) + (i - 2883584);
      float4 v = *src;
      uint2 o;
      o.x = cvtpk(v.x, v.y);
      o.y = cvtpk(v.z, v.w);
      reinterpret_cast<uint2*>(dst)[i] = o;
    }
  } else {
    int i = (bid - 2048) * 256 + threadIdx.x;   // 0 .. 65535
    float v = ropef[i];
    tbl[i] = make_float2(cosf(v), sinf(v));
  }
}

// scale (D^-0.5 = 1/8) * log2(e): softmax computed with exp2
#define QSCALE 0.18033688011112042f

// ---------------- GEMM core: C[128x256] = A[128xK] * B[256xK]^T, K=1024 ----------------
// R12 config (empirical best): BM=128 BN=256 BK=64, 1024 threads / 16 waves
// (4M x 4N; per-wave 32x64, acc[2][4]).  Double-buffered; stage(k+1) before
// compute(k); one barrier per K-step.  LDS (dynamic): As[2][128*64], Bs[2][256*64].
__device__ __forceinline__ void gemm_main(const short* __restrict__ A,
                                          const short* __restrict__ Bm,
                                          short* As, short* Bs,
                                          floatx4 (&acc)[2][4],
                                          int bx, int by) {
  const int tid = threadIdx.x;
  const int wid = tid >> 6, lane = tid & 63;
  const int g = lane >> 4, l15 = lane & 15;
  const int wr = wid >> 2, wc = wid & 3;          // 4 row-bands(32) x 4 col-bands(64)
  const size_t trow = (size_t)by * 128, tcol = (size_t)bx * 256;
  floatx4 zero = {0.f, 0.f, 0.f, 0.f};
  #pragma unroll
  for (int i = 0; i < 2; ++i)
    #pragma unroll
    for (int j = 0; j < 4; ++j) acc[i][j] = zero;

  auto stage = [&](int buf, int k0) {
    {
      const int cb = wid * 64;                // A: 1024 chunks of 16B
      const int c  = cb + lane;
      const int r  = c >> 3, s = c & 7;
      const int koff = k0 + ((s ^ (r & 7)) << 3);
      gld16(A + (trow + r) * 1024 + koff, As + buf * 8192 + (size_t)cb * 8);
    }
    #pragma unroll
    for (int i = 0; i < 2; ++i) {
      const int cb = (i * 16 + wid) * 64;     // B: 2048 chunks of 16B
      const int c  = cb + lane;
      const int r  = c >> 3, s = c & 7;
      const int koff = k0 + ((s ^ (r & 7)) << 3);
      gld16(Bm + (tcol + r) * 1024 + koff, Bs + buf * 16384 + (size_t)cb * 8);
    }
  };

  stage(0, 0);
  __syncthreads();

  for (int t = 0; t < 16; ++t) {
    const int buf = t & 1;
    if (t < 15) stage(buf ^ 1, (t + 1) * 64);     // loads fly under compute
    const short* Ab = As + buf * 8192;
    const short* Bb = Bs + buf * 16384;
    #pragma unroll
    for (int ks = 0; ks < 2; ++ks) {
      bf16x8 af[2], bfr[4];
      #pragma unroll
      for (int mi = 0; mi < 2; ++mi) {
        int row = wr * 32 + mi * 16 + l15;
        int ch  = (ks * 4 + g) ^ (row & 7);
        af[mi] = *reinterpret_cast<const bf16x8*>(Ab + row * 64 + ch * 8);
      }
      #pragma unroll
      for (int nt = 0; nt < 4; ++nt) {
        int row = wc * 64 + nt * 16 + l15;
        int ch  = (ks * 4 + g) ^ (row & 7);
        bfr[nt] = *reinterpret_cast<const bf16x8*>(Bb + row * 64 + ch * 8);
      }
      __builtin_amdgcn_s_setprio(1);
      #pragma unroll
      for (int mi = 0; mi < 2; ++mi)
        #pragma unroll
        for (int nt = 0; nt < 4; ++nt)
          acc[mi][nt] = __builtin_amdgcn_mfma_f32_16x16x32_bf16(af[mi], bfr[nt],
                                                                acc[mi][nt], 0, 0, 0);
      __builtin_amdgcn_s_setprio(0);
    }
    __syncthreads();   // staged t+1 complete (barrier drains vmcnt); buf reusable
  }
}

// QKV GEMM with fused RoPE epilogue.  bx: 0..3 -> q, 4..7 -> k, 8..11 -> v.
// q/k written [bh][n][d] with RoPE (q also pre-scaled); v written TRANSPOSED [bh][d][n].
__global__ __launch_bounds__(1024, 4) void gemm_qkv_k(const short* __restrict__ A,
                                                      const short* __restrict__ Bm,
                                                      const float2* __restrict__ tbl,
                                                      short* __restrict__ qo,
                                                      short* __restrict__ ko,
                                                      short* __restrict__ vt) {
  extern __shared__ __align__(16) short smem[];
  short* As = smem;             // 2 x 128*64
  short* Bs = smem + 16384;     // 2 x 256*64
  // XCD-aware bijective swizzle: nwg = 12*64 = 768, 768 % 8 == 0.
  const int id  = blockIdx.y * 12 + blockIdx.x;
  const int sid = (id & 7) * 96 + (id >> 3);
  const int bx  = sid % 12, by = sid / 12;
  floatx4 acc[2][4];
  gemm_main(A, Bm, As, Bs, acc, bx, by);

  const int tid = threadIdx.x;
  const int wid = tid >> 6, lane = tid & 63;
  const int g = lane >> 4, l15 = lane & 15;
  const int wr = wid >> 2, wc = wid & 3;
  const int trow = by * 128, tcol = bx * 256;
  const int which = bx >> 2;

  if (which < 2) {
    short* dst = which == 0 ? qo : ko;
    const float sc = which == 0 ? QSCALE : 1.0f;
    #pragma unroll
    for (int nt = 0; nt < 2; ++nt) {              // pairs (nt, nt+2) = (d, d+32)
      int col = tcol + wc * 64 + nt * 16 + l15;
      int hc = col & 1023, h = hc >> 6, d1 = hc & 63;   // d1 in [0,32)
      #pragma unroll
      for (int mi = 0; mi < 2; ++mi)
        #pragma unroll
        for (int r = 0; r < 4; ++r) {
          int rowg = trow + wr * 32 + mi * 16 + g * 4 + r;
          int b = rowg >> 10, n = rowg & 1023;
          float a1 = acc[mi][nt][r], a2 = acc[mi][nt + 2][r];
          float2 c1 = tbl[n * 64 + d1];
          float2 c2 = tbl[n * 64 + d1 + 32];
          float o1 = (a1 * c1.x - a2 * c1.y) * sc;
          float o2 = (a2 * c2.x + a1 * c2.y) * sc;
          size_t base = ((size_t)(b * 16 + h) * 1024 + n) * 64;
          dst[base + d1]      = f2bf(o1);
          dst[base + d1 + 32] = f2bf(o2);
        }
    }
  } else {
    // V^T [bh][d=64][n=1024]; acc reg axis r = consecutive n -> 8B packed stores
    #pragma unroll
    for (int nt = 0; nt < 4; ++nt) {
      int col = tcol + wc * 64 + nt * 16 + l15;
      int hc = col & 1023, h = hc >> 6, d = hc & 63;
      #pragma unroll
      for (int mi = 0; mi < 2; ++mi) {
        int rowg = trow + wr * 32 + mi * 16 + g * 4;
        int b = rowg >> 10, n0 = rowg & 1023;
        ushort4 pk;
        pk.x = (unsigned short)f2bf(acc[mi][nt][0]);
        pk.y = (unsigned short)f2bf(acc[mi][nt][1]);
        pk.z = (unsigned short)f2bf(acc[mi][nt][2]);
        pk.w = (unsigned short)f2bf(acc[mi][nt][3]);
        *reinterpret_cast<ushort4*>((unsigned short*)vt +
            ((size_t)(b * 16 + h) * 64 + d) * 1024 + n0) = pk;
      }
    }
  }
}

// Proj GEMM: attn_out bf16 [8192x1024] x proj_w bf16 [1024x1024]^T + bias -> fp32
__global__ __launch_bounds__(1024, 4) void gemm_proj_k(const short* __restrict__ A,
                                                       const short* __restrict__ Bm,
                                                       const float* __restrict__ pb,
                                                       float* __restrict__ out) {
  extern __shared__ __align__(16) short smem[];
  short* As = smem;             // 2 x 128*64
  short* Bs = smem + 16384;     // 2 x 256*64
  // XCD-aware bijective swizzle: nwg = 4*64 = 256, 256 % 8 == 0.
  const int id  = blockIdx.y * 4 + blockIdx.x;
  const int sid = (id & 7) * 32 + (id >> 3);
  const int bx  = sid % 4, by = sid / 4;
  floatx4 acc[2][4];
  gemm_main(A, Bm, As, Bs, acc, bx, by);

  const int tid = threadIdx.x;
  const int wid = tid >> 6, lane = tid & 63;
  const int g = lane >> 4, l15 = lane & 15;
  const int wr = wid >> 2, wc = wid & 3;
  const int trow = by * 128, tcol = bx * 256;
  #pragma unroll
  for (int nt = 0; nt < 4; ++nt) {
    int col = tcol + wc * 64 + nt * 16 + l15;
    float bias = pb[col];
    #pragma unroll
    for (int mi = 0; mi < 2; ++mi)
      #pragma unroll
      for (int r = 0; r < 4; ++r) {
        int rowg = trow + wr * 32 + mi * 16 + g * 4 + r;
        out[(size_t)rowg * 1024 + col] = acc[mi][nt][r] + bias;
      }
  }
}

// ---------------- flash attention (swapped-QK^T, no-max softmax, 256-q blocks) --------
// R18 version (verified): grid (128 bh, 4 q-tiles of 256); FOUR 64-q halves share each
// K/V tile's ds_reads; two k=32 slices bound VGPR; 3-buf counted-vmcnt staging.
__global__ __launch_bounds__(256) void attn_kernel(const short* __restrict__ qs,
                                                   const short* __restrict__ ksrc,
                                                   const short* __restrict__ vt,
                                                   short* __restrict__ aout) {
  __shared__ __align__(16) short Kl[3][64 * 64];
  __shared__ __align__(16) short Vl[3][64 * 64];

  const int tid = threadIdx.x, wid = tid >> 6, lane = tid & 63;
  const int g = lane >> 4, l15 = lane & 15;
  const int bh = blockIdx.x, q0 = blockIdx.y * 256;
  const size_t bhoff = (size_t)bh * 1024 * 64;
  const short* Kb = ksrc + bhoff;          // [n][d]
  const short* Vb = vt + bhoff;            // [d][n]
  const int slb = (lane & 48) + ((lane >> 4) << 2);

  const short* QpA = qs + bhoff + (size_t)(q0 + wid * 16 + l15) * 64 + g * 8;
  bf16x8 qA0 = *reinterpret_cast<const bf16x8*>(QpA);
  bf16x8 qA1 = *reinterpret_cast<const bf16x8*>(QpA + 32);
  bf16x8 qB0 = *reinterpret_cast<const bf16x8*>(QpA + 64 * 64);
  bf16x8 qB1 = *reinterpret_cast<const bf16x8*>(QpA + 64 * 64 + 32);
  bf16x8 qC0 = *reinterpret_cast<const bf16x8*>(QpA + 128 * 64);
  bf16x8 qC1 = *reinterpret_cast<const bf16x8*>(QpA + 128 * 64 + 32);
  bf16x8 qD0 = *reinterpret_cast<const bf16x8*>(QpA + 192 * 64);
  bf16x8 qD1 = *reinterpret_cast<const bf16x8*>(QpA + 192 * 64 + 32);

  floatx4 oA[4], oB[4], oC[4], oD[4];
  floatx4 zero = {0.f, 0.f, 0.f, 0.f};
  #pragma unroll
  for (int i = 0; i < 4; ++i) { oA[i] = zero; oB[i] = zero; oC[i] = zero; oD[i] = zero; }
  float lrunA = 0.f, lrunB = 0.f, lrunC = 0.f, lrunD = 0.f;

  auto stage = [&](int buf, int t) {
    #pragma unroll
    for (int i = 0; i < 2; ++i) {
      const int cb = (i * 4 + wid) * 64;         // wave-uniform chunk base
      const int c = cb + lane;
      const int r = c >> 3, s = c & 7;
      const int off = (s ^ (r & 7)) << 3;        // pre-swizzled source
      gld16(Kb + (size_t)(t * 64 + r) * 64 + off, &Kl[buf][cb * 8]);
      gld16(Vb + (size_t)r * 1024 + t * 64 + off, &Vl[buf][cb * 8]);
    }
  };

#define SOFTSLICE(s_, lrun, pa)                                                \
  do {                                                                         \
    float p0 = pexp(s_[0][0]), p1 = pexp(s_[0][1]);                            \
    float p2 = pexp(s_[0][2]), p3 = pexp(s_[0][3]);                            \
    float p4 = pexp(s_[1][0]), p5 = pexp(s_[1][1]);                            \
    float p6 = pexp(s_[1][2]), p7 = pexp(s_[1][3]);                            \
    lrun += ((p0 + p1) + (p2 + p3)) + ((p4 + p5) + (p6 + p7));                 \
    unsigned wa0 = cvtpk(p0, p1), wa1 = cvtpk(p2, p3);                         \
    unsigned wb0 = cvtpk(p4, p5), wb1 = cvtpk(p6, p7);                         \
    u32x2 y0 = __builtin_amdgcn_permlane32_swap(wa0, wb0, false, false);       \
    u32x2 z0 = __builtin_amdgcn_permlane16_swap(y0[0], y0[1], false, false);   \
    u32x2 y1 = __builtin_amdgcn_permlane32_swap(wa1, wb1, false, false);       \
    u32x2 z1 = __builtin_amdgcn_permlane16_swap(y1[0], y1[1], false, false);   \
    u32x4 aw = {z0[0], z1[0], z0[1], z1[1]};                                   \
    pa = __builtin_bit_cast(bf16x8, aw);                                       \
  } while (0)

#define QKSLICE(base, sA_, sB_, sC_, sD_)                                      \
  __builtin_amdgcn_s_setprio(1);                                               \
  _Pragma("unroll")                                                            \
  for (int kk = 0; kk < 2; ++kk) {                                             \
    int krow = (base + kk) * 16 + l15;                                         \
    int ch0 = (g ^ (krow & 7)) << 3, ch1 = ((4 + g) ^ (krow & 7)) << 3;        \
    bf16x8 kf0 = *reinterpret_cast<const bf16x8*>(&Kl[btop][krow * 64 + ch0]); \
    sA_[kk] = __builtin_amdgcn_mfma_f32_16x16x32_bf16(kf0, qA0, sA_[kk],0,0,0);\
    sB_[kk] = __builtin_amdgcn_mfma_f32_16x16x32_bf16(kf0, qB0, sB_[kk],0,0,0);\
    sC_[kk] = __builtin_amdgcn_mfma_f32_16x16x32_bf16(kf0, qC0, sC_[kk],0,0,0);\
    sD_[kk] = __builtin_amdgcn_mfma_f32_16x16x32_bf16(kf0, qD0, sD_[kk],0,0,0);\
    bf16x8 kf1 = *reinterpret_cast<const bf16x8*>(&Kl[btop][krow * 64 + ch1]); \
    sA_[kk] = __builtin_amdgcn_mfma_f32_16x16x32_bf16(kf1, qA1, sA_[kk],0,0,0);\
    sB_[kk] = __builtin_amdgcn_mfma_f32_16x16x32_bf16(kf1, qB1, sB_[kk],0,0,0);\
    sC_[kk] = __builtin_amdgcn_mfma_f32_16x16x32_bf16(kf1, qC1, sC_[kk],0,0,0);\
    sD_[kk] = __builtin_amdgcn_mfma_f32_16x16x32_bf16(kf1, qD1, sD_[kk],0,0,0);\
  }                                                                            \
  __builtin_amdgcn_s_setprio(0);

#define PVSLICE(chsel, paA_, paB_, paC_, paD_)                                 \
  __builtin_amdgcn_s_setprio(1);                                               \
  _Pragma("unroll")                                                            \
  for (int nt = 0; nt < 4; ++nt) {                                             \
    int row = nt * 16 + l15;                                                   \
    int ch = (((chsel) + g) ^ (row & 7)) << 3;                                 \
    bf16x8 vf = *reinterpret_cast<const bf16x8*>(&Vl[btop][row * 64 + ch]);    \
    oA[nt] = __builtin_amdgcn_mfma_f32_16x16x32_bf16(paA_, vf, oA[nt],0,0,0);  \
    oB[nt] = __builtin_amdgcn_mfma_f32_16x16x32_bf16(paB_, vf, oB[nt],0,0,0);  \
    oC[nt] = __builtin_amdgcn_mfma_f32_16x16x32_bf16(paC_, vf, oC[nt],0,0,0);  \
    oD[nt] = __builtin_amdgcn_mfma_f32_16x16x32_bf16(paD_, vf, oD[nt],0,0,0);  \
  }                                                                            \
  __builtin_amdgcn_s_setprio(0);

  stage(0, 0);
  stage(1, 1);
  asm volatile("s_waitcnt vmcnt(4)" ::: "memory");
  __builtin_amdgcn_s_barrier();
  asm volatile("" ::: "memory");

  int btop = 0;
  for (int t = 0; t < 16; ++t) {
    if (t < 14) {
      int bnx = btop + 2; if (bnx >= 3) bnx -= 3;
      stage(bnx, t + 2);                       // loads span 2 compute phases
    }

    {  // slice 0: k = 0..31
      floatx4 sA[2], sB[2], sC[2], sD[2];
      #pragma unroll
      for (int kk = 0; kk < 2; ++kk) { sA[kk]=zero; sB[kk]=zero; sC[kk]=zero; sD[kk]=zero; }
      QKSLICE(0, sA, sB, sC, sD);
      bf16x8 paA, paB, paC, paD;
      SOFTSLICE(sA, lrunA, paA);
      SOFTSLICE(sB, lrunB, paB);
      SOFTSLICE(sC, lrunC, paC);
      SOFTSLICE(sD, lrunD, paD);
      PVSLICE(0, paA, paB, paC, paD);
    }
    {  // slice 1: k = 32..63
      floatx4 sA[2], sB[2], sC[2], sD[2];
      #pragma unroll
      for (int kk = 0; kk < 2; ++kk) { sA[kk]=zero; sB[kk]=zero; sC[kk]=zero; sD[kk]=zero; }
      QKSLICE(2, sA, sB, sC, sD);
      bf16x8 paA, paB, paC, paD;
      SOFTSLICE(sA, lrunA, paA);
      SOFTSLICE(sB, lrunB, paB);
      SOFTSLICE(sC, lrunC, paC);
      SOFTSLICE(sD, lrunD, paD);
      PVSLICE(4, paA, paB, paC, paD);
    }

    if (t < 15) {
      if (t < 14) asm volatile("s_waitcnt vmcnt(4)" ::: "memory");
      else        asm volatile("s_waitcnt vmcnt(0)" ::: "memory");
      __builtin_amdgcn_s_barrier();
      asm volatile("" ::: "memory");
    }
    btop = btop + 1 == 3 ? 0 : btop + 1;
  }

  // ---- epilogue ----
  const int b = bh >> 4, h = bh & 15;
  lrunA += __shfl_xor(lrunA, 16); lrunA += __shfl_xor(lrunA, 32);
  lrunB += __shfl_xor(lrunB, 16); lrunB += __shfl_xor(lrunB, 32);
  lrunC += __shfl_xor(lrunC, 16); lrunC += __shfl_xor(lrunC, 32);
  lrunD += __shfl_xor(lrunD, 16); lrunD += __shfl_xor(lrunD, 32);
  float invA = 1.f / lrunA, invB = 1.f / lrunB;
  float invC = 1.f / lrunC, invD = 1.f / lrunD;
  #pragma unroll
  for (int r = 0; r < 4; ++r) {
    float irA = __shfl(invA, slb + r);
    float irB = __shfl(invB, slb + r);
    float irC = __shfl(invC, slb + r);
    float irD = __shfl(invD, slb + r);
    int nA = q0 + wid * 16 + g * 4 + r;
    size_t baseA = ((size_t)(b * 1024) + nA) * 1024 + h * 64;
    size_t baseB = baseA + (size_t)64 * 1024;
    size_t baseC = baseA + (size_t)128 * 1024;
    size_t baseD = baseA + (size_t)192 * 1024;
    #pragma unroll
    for (int nt = 0; nt < 4; ++nt) {
      aout[baseA + nt * 16 + l15] = f2bf(oA[nt][r] * irA);
      aout[baseB + nt * 16 + l15] = f2bf(oB[nt][r] * irB);
      aout[baseC + nt * 16 + l15] = f2bf(oC[nt][r] * irC);
      aout[baseD + nt * 16 + l15] = f2bf(oD[nt][r] * irD);
    }
  }
#undef SOFTSLICE
#undef QKSLICE
#undef PVSLICE
}

// ---------------------------------------------------------------------------
extern "C" void kernel_launch(void* const* d_in, const int* in_sizes, int n_in,
                              void* d_out, int out_size, void* d_ws, size_t ws_size,
                              hipStream_t stream) {
  const float* x      = (const float*)d_in[0];   // [8,1024,1024]
  const float* ropef  = (const float*)d_in[1];   // [1,1024,1,64]
  const float* qkv_w  = (const float*)d_in[2];   // [3072,1024]
  const float* proj_w = (const float*)d_in[3];   // [1024,1024]
  const float* proj_b = (const float*)d_in[4];   // [1024]
  float* out = (float*)d_out;

  char* ws = (char*)d_ws;
  short*  xb  = (short*)(ws + 0);            // 16 MB  x bf16        (contiguous with)
  short*  wqb = (short*)(ws + 16777216);     //  6 MB  qkv_w bf16    (contiguous with)
  short*  wpb = (short*)(ws + 23068672);     //  2 MB  proj_w bf16
  short*  qb  = (short*)(ws + 25165824);     // 16 MB  q [bh][n][d] (RoPE+scale)
  short*  kb  = (short*)(ws + 41943040);     // 16 MB  k [bh][n][d] (RoPE)
  short*  vtb = (short*)(ws + 58720256);     // 16 MB  v^T [bh][d][n]
  short*  aob = (short*)(ws + 75497472);     // 16 MB  attn out bf16 [B][N][C]
  float2* tbl = (float2*)(ws + 92274688);    // 512 KB cos/sin table

  prep_all<<<2304, 256, 0, stream>>>(x, qkv_w, proj_w, xb, ropef, tbl);

  gemm_qkv_k<<<dim3(12, 64), 1024, 98304, stream>>>(xb, wqb, tbl, qb, kb, vtb);
  attn_kernel<<<dim3(128, 4), 256, 0, stream>>>(qb, kb, vtb, aob);
  gemm_proj_k<<<dim3(4, 64), 1024, 98304, stream>>>(aob, wpb, proj_b, out);
}

// Round 21
// 155.035 us; speedup vs baseline: 1.0313x; 1.0042x over previous
//
#include <hip/hip_runtime.h>

// ---------------------------------------------------------------------------
// Fused attention block: qkv-proj(+RoPE fused) -> flash attention -> out-proj
// B=8 N=1024 C=1024 H=16 D=64.  All matmuls bf16 MFMA 16x16x32, fp32 acc.
// FINAL (verified 155.7 us): R12 GEMM (occupancy-optimal 16-wave 128x256) +
// R18 attn (4-half shared-ds_read, no-max softmax, permlane P-redistribute) +
// R19 grid-stride cvtpk prep.  Session 275 -> 155.7 us (1.77x).
// ---------------------------------------------------------------------------

typedef __attribute__((ext_vector_type(8))) short bf16x8;
typedef __attribute__((ext_vector_type(4))) float floatx4;
typedef __attribute__((ext_vector_type(4))) unsigned int u32x4;
typedef __attribute__((ext_vector_type(2))) unsigned int u32x2;

__device__ __forceinline__ void gld16(const void* g, void* l) {
  __builtin_amdgcn_global_load_lds((const __attribute__((address_space(1))) void*)g,
                                   (__attribute__((address_space(3))) void*)l, 16, 0, 0);
}

__device__ __forceinline__ short f2bf(float f) {          // RNE fp32->bf16
  unsigned u = __builtin_bit_cast(unsigned, f);
  u = (u + 0x7FFFu + ((u >> 16) & 1u)) >> 16;
  return (short)u;
}
__device__ __forceinline__ unsigned cvtpk(float lo, float hi) {
  unsigned r;
  asm("v_cvt_pk_bf16_f32 %0, %1, %2" : "=v"(r) : "v"(lo), "v"(hi));
  return r;
}
__device__ __forceinline__ float pexp(float x) {          // raw v_exp_f32 (2^x)
  float r;
  asm("v_exp_f32 %0, %1" : "=v"(r) : "v"(x));
  return r;
}

// ---------------- prep: fp32->bf16 (x|qkv_w|proj_w) + RoPE cos/sin table ----------------
__global__ __launch_bounds__(256) void prep_all(const float* __restrict__ sx,
                                                const float* __restrict__ sq,
                                                const float* __restrict__ sp,
                                                short* __restrict__ dst,
                                                const float* __restrict__ ropef,
                                                float2* __restrict__ tbl) {
  int bid = blockIdx.x;
  if (bid < 2048) {
    for (int i = bid * 256 + threadIdx.x; i < 3145728; i += 2048 * 256) {
      const float4* src;
      if (i < 2097152)      src = reinterpret_cast<const float4*>(sx) + i;
      else if (i < 2883584) src = reinterpret_cast<const float4*>(sq) + (i - 2097152);
      else                  src = reinterpret_cast<const float4*>(sp) + (i - 2883584);
      float4 v = *src;
      uint2 o;
      o.x = cvtpk(v.x, v.y);
      o.y = cvtpk(v.z, v.w);
      reinterpret_cast<uint2*>(dst)[i] = o;
    }
  } else {
    int i = (bid - 2048) * 256 + threadIdx.x;   // 0 .. 65535
    float v = ropef[i];
    tbl[i] = make_float2(cosf(v), sinf(v));
  }
}

// scale (D^-0.5 = 1/8) * log2(e): softmax computed with exp2
#define QSCALE 0.18033688011112042f

// ---------------- GEMM core: C[128x256] = A[128xK] * B[256xK]^T, K=1024 ----------------
// R12 config (empirical best): BM=128 BN=256 BK=64, 1024 threads / 16 waves
// (4M x 4N; per-wave 32x64, acc[2][4]).  Double-buffered; stage(k+1) before
// compute(k); one barrier per K-step.  LDS (dynamic): As[2][128*64], Bs[2][256*64].
__device__ __forceinline__ void gemm_main(const short* __restrict__ A,
                                          const short* __restrict__ Bm,
                                          short* As, short* Bs,
                                          floatx4 (&acc)[2][4],
                                          int bx, int by) {
  const int tid = threadIdx.x;
  const int wid = tid >> 6, lane = tid & 63;
  const int g = lane >> 4, l15 = lane & 15;
  const int wr = wid >> 2, wc = wid & 3;          // 4 row-bands(32) x 4 col-bands(64)
  const size_t trow = (size_t)by * 128, tcol = (size_t)bx * 256;
  floatx4 zero = {0.f, 0.f, 0.f, 0.f};
  #pragma unroll
  for (int i = 0; i < 2; ++i)
    #pragma unroll
    for (int j = 0; j < 4; ++j) acc[i][j] = zero;

  auto stage = [&](int buf, int k0) {
    {
      const int cb = wid * 64;                // A: 1024 chunks of 16B
      const int c  = cb + lane;
      const int r  = c >> 3, s = c & 7;
      const int koff = k0 + ((s ^ (r & 7)) << 3);
      gld16(A + (trow + r) * 1024 + koff, As + buf * 8192 + (size_t)cb * 8);
    }
    #pragma unroll
    for (int i = 0; i < 2; ++i) {
      const int cb = (i * 16 + wid) * 64;     // B: 2048 chunks of 16B
      const int c  = cb + lane;
      const int r  = c >> 3, s = c & 7;
      const int koff = k0 + ((s ^ (r & 7)) << 3);
      gld16(Bm + (tcol + r) * 1024 + koff, Bs + buf * 16384 + (size_t)cb * 8);
    }
  };

  stage(0, 0);
  __syncthreads();

  for (int t = 0; t < 16; ++t) {
    const int buf = t & 1;
    if (t < 15) stage(buf ^ 1, (t + 1) * 64);     // loads fly under compute
    const short* Ab = As + buf * 8192;
    const short* Bb = Bs + buf * 16384;
    #pragma unroll
    for (int ks = 0; ks < 2; ++ks) {
      bf16x8 af[2], bfr[4];
      #pragma unroll
      for (int mi = 0; mi < 2; ++mi) {
        int row = wr * 32 + mi * 16 + l15;
        int ch  = (ks * 4 + g) ^ (row & 7);
        af[mi] = *reinterpret_cast<const bf16x8*>(Ab + row * 64 + ch * 8);
      }
      #pragma unroll
      for (int nt = 0; nt < 4; ++nt) {
        int row = wc * 64 + nt * 16 + l15;
        int ch  = (ks * 4 + g) ^ (row & 7);
        bfr[nt] = *reinterpret_cast<const bf16x8*>(Bb + row * 64 + ch * 8);
      }
      __builtin_amdgcn_s_setprio(1);
      #pragma unroll
      for (int mi = 0; mi < 2; ++mi)
        #pragma unroll
        for (int nt = 0; nt < 4; ++nt)
          acc[mi][nt] = __builtin_amdgcn_mfma_f32_16x16x32_bf16(af[mi], bfr[nt],
                                                                acc[mi][nt], 0, 0, 0);
      __builtin_amdgcn_s_setprio(0);
    }
    __syncthreads();   // staged t+1 complete (barrier drains vmcnt); buf reusable
  }
}

// QKV GEMM with fused RoPE epilogue.  bx: 0..3 -> q, 4..7 -> k, 8..11 -> v.
// q/k written [bh][n][d] with RoPE (q also pre-scaled); v written TRANSPOSED [bh][d][n].
__global__ __launch_bounds__(1024, 4) void gemm_qkv_k(const short* __restrict__ A,
                                                      const short* __restrict__ Bm,
                                                      const float2* __restrict__ tbl,
                                                      short* __restrict__ qo,
                                                      short* __restrict__ ko,
                                                      short* __restrict__ vt) {
  extern __shared__ __align__(16) short smem[];
  short* As = smem;             // 2 x 128*64
  short* Bs = smem + 16384;     // 2 x 256*64
  // XCD-aware bijective swizzle: nwg = 12*64 = 768, 768 % 8 == 0.
  const int id  = blockIdx.y * 12 + blockIdx.x;
  const int sid = (id & 7) * 96 + (id >> 3);
  const int bx  = sid % 12, by = sid / 12;
  floatx4 acc[2][4];
  gemm_main(A, Bm, As, Bs, acc, bx, by);

  const int tid = threadIdx.x;
  const int wid = tid >> 6, lane = tid & 63;
  const int g = lane >> 4, l15 = lane & 15;
  const int wr = wid >> 2, wc = wid & 3;
  const int trow = by * 128, tcol = bx * 256;
  const int which = bx >> 2;

  if (which < 2) {
    short* dst = which == 0 ? qo : ko;
    const float sc = which == 0 ? QSCALE : 1.0f;
    #pragma unroll
    for (int nt = 0; nt < 2; ++nt) {              // pairs (nt, nt+2) = (d, d+32)
      int col = tcol + wc * 64 + nt * 16 + l15;
      int hc = col & 1023, h = hc >> 6, d1 = hc & 63;   // d1 in [0,32)
      #pragma unroll
      for (int mi = 0; mi < 2; ++mi)
        #pragma unroll
        for (int r = 0; r < 4; ++r) {
          int rowg = trow + wr * 32 + mi * 16 + g * 4 + r;
          int b = rowg >> 10, n = rowg & 1023;
          float a1 = acc[mi][nt][r], a2 = acc[mi][nt + 2][r];
          float2 c1 = tbl[n * 64 + d1];
          float2 c2 = tbl[n * 64 + d1 + 32];
          float o1 = (a1 * c1.x - a2 * c1.y) * sc;
          float o2 = (a2 * c2.x + a1 * c2.y) * sc;
          size_t base = ((size_t)(b * 16 + h) * 1024 + n) * 64;
          dst[base + d1]      = f2bf(o1);
          dst[base + d1 + 32] = f2bf(o2);
        }
    }
  } else {
    // V^T [bh][d=64][n=1024]; acc reg axis r = consecutive n -> 8B packed stores
    #pragma unroll
    for (int nt = 0; nt < 4; ++nt) {
      int col = tcol + wc * 64 + nt * 16 + l15;
      int hc = col & 1023, h = hc >> 6, d = hc & 63;
      #pragma unroll
      for (int mi = 0; mi < 2; ++mi) {
        int rowg = trow + wr * 32 + mi * 16 + g * 4;
        int b = rowg >> 10, n0 = rowg & 1023;
        ushort4 pk;
        pk.x = (unsigned short)f2bf(acc[mi][nt][0]);
        pk.y = (unsigned short)f2bf(acc[mi][nt][1]);
        pk.z = (unsigned short)f2bf(acc[mi][nt][2]);
        pk.w = (unsigned short)f2bf(acc[mi][nt][3]);
        *reinterpret_cast<ushort4*>((unsigned short*)vt +
            ((size_t)(b * 16 + h) * 64 + d) * 1024 + n0) = pk;
      }
    }
  }
}

// Proj GEMM: attn_out bf16 [8192x1024] x proj_w bf16 [1024x1024]^T + bias -> fp32
__global__ __launch_bounds__(1024, 4) void gemm_proj_k(const short* __restrict__ A,
                                                       const short* __restrict__ Bm,
                                                       const float* __restrict__ pb,
                                                       float* __restrict__ out) {
  extern __shared__ __align__(16) short smem[];
  short* As = smem;             // 2 x 128*64
  short* Bs = smem + 16384;     // 2 x 256*64
  // XCD-aware bijective swizzle: nwg = 4*64 = 256, 256 % 8 == 0.
  const int id  = blockIdx.y * 4 + blockIdx.x;
  const int sid = (id & 7) * 32 + (id >> 3);
  const int bx  = sid % 4, by = sid / 4;
  floatx4 acc[2][4];
  gemm_main(A, Bm, As, Bs, acc, bx, by);

  const int tid = threadIdx.x;
  const int wid = tid >> 6, lane = tid & 63;
  const int g = lane >> 4, l15 = lane & 15;
  const int wr = wid >> 2, wc = wid & 3;
  const int trow = by * 128, tcol = bx * 256;
  #pragma unroll
  for (int nt = 0; nt < 4; ++nt) {
    int col = tcol + wc * 64 + nt * 16 + l15;
    float bias = pb[col];
    #pragma unroll
    for (int mi = 0; mi < 2; ++mi)
      #pragma unroll
      for (int r = 0; r < 4; ++r) {
        int rowg = trow + wr * 32 + mi * 16 + g * 4 + r;
        out[(size_t)rowg * 1024 + col] = acc[mi][nt][r] + bias;
      }
  }
}

// ---------------- flash attention (swapped-QK^T, no-max softmax, 256-q blocks) --------
// grid (128 bh, 4 q-tiles of 256); FOUR 64-q halves share each K/V tile's ds_reads;
// two k=32 slices bound VGPR; 3-buf counted-vmcnt staging (R10-verified).
__global__ __launch_bounds__(256) void attn_kernel(const short* __restrict__ qs,
                                                   const short* __restrict__ ksrc,
                                                   const short* __restrict__ vt,
                                                   short* __restrict__ aout) {
  __shared__ __align__(16) short Kl[3][64 * 64];
  __shared__ __align__(16) short Vl[3][64 * 64];

  const int tid = threadIdx.x, wid = tid >> 6, lane = tid & 63;
  const int g = lane >> 4, l15 = lane & 15;
  const int bh = blockIdx.x, q0 = blockIdx.y * 256;
  const size_t bhoff = (size_t)bh * 1024 * 64;
  const short* Kb = ksrc + bhoff;          // [n][d]
  const short* Vb = vt + bhoff;            // [d][n]
  const int slb = (lane & 48) + ((lane >> 4) << 2);

  const short* QpA = qs + bhoff + (size_t)(q0 + wid * 16 + l15) * 64 + g * 8;
  bf16x8 qA0 = *reinterpret_cast<const bf16x8*>(QpA);
  bf16x8 qA1 = *reinterpret_cast<const bf16x8*>(QpA + 32);
  bf16x8 qB0 = *reinterpret_cast<const bf16x8*>(QpA + 64 * 64);
  bf16x8 qB1 = *reinterpret_cast<const bf16x8*>(QpA + 64 * 64 + 32);
  bf16x8 qC0 = *reinterpret_cast<const bf16x8*>(QpA + 128 * 64);
  bf16x8 qC1 = *reinterpret_cast<const bf16x8*>(QpA + 128 * 64 + 32);
  bf16x8 qD0 = *reinterpret_cast<const bf16x8*>(QpA + 192 * 64);
  bf16x8 qD1 = *reinterpret_cast<const bf16x8*>(QpA + 192 * 64 + 32);

  floatx4 oA[4], oB[4], oC[4], oD[4];
  floatx4 zero = {0.f, 0.f, 0.f, 0.f};
  #pragma unroll
  for (int i = 0; i < 4; ++i) { oA[i] = zero; oB[i] = zero; oC[i] = zero; oD[i] = zero; }
  float lrunA = 0.f, lrunB = 0.f, lrunC = 0.f, lrunD = 0.f;

  auto stage = [&](int buf, int t) {
    #pragma unroll
    for (int i = 0; i < 2; ++i) {
      const int cb = (i * 4 + wid) * 64;         // wave-uniform chunk base
      const int c = cb + lane;
      const int r = c >> 3, s = c & 7;
      const int off = (s ^ (r & 7)) << 3;        // pre-swizzled source
      gld16(Kb + (size_t)(t * 64 + r) * 64 + off, &Kl[buf][cb * 8]);
      gld16(Vb + (size_t)r * 1024 + t * 64 + off, &Vl[buf][cb * 8]);
    }
  };

#define SOFTSLICE(s_, lrun, pa)                                                \
  do {                                                                         \
    float p0 = pexp(s_[0][0]), p1 = pexp(s_[0][1]);                            \
    float p2 = pexp(s_[0][2]), p3 = pexp(s_[0][3]);                            \
    float p4 = pexp(s_[1][0]), p5 = pexp(s_[1][1]);                            \
    float p6 = pexp(s_[1][2]), p7 = pexp(s_[1][3]);                            \
    lrun += ((p0 + p1) + (p2 + p3)) + ((p4 + p5) + (p6 + p7));                 \
    unsigned wa0 = cvtpk(p0, p1), wa1 = cvtpk(p2, p3);                         \
    unsigned wb0 = cvtpk(p4, p5), wb1 = cvtpk(p6, p7);                         \
    u32x2 y0 = __builtin_amdgcn_permlane32_swap(wa0, wb0, false, false);       \
    u32x2 z0 = __builtin_amdgcn_permlane16_swap(y0[0], y0[1], false, false);   \
    u32x2 y1 = __builtin_amdgcn_permlane32_swap(wa1, wb1, false, false);       \
    u32x2 z1 = __builtin_amdgcn_permlane16_swap(y1[0], y1[1], false, false);   \
    u32x4 aw = {z0[0], z1[0], z0[1], z1[1]};                                   \
    pa = __builtin_bit_cast(bf16x8, aw);                                       \
  } while (0)

#define QKSLICE(base, sA_, sB_, sC_, sD_)                                      \
  __builtin_amdgcn_s_setprio(1);                                               \
  _Pragma("unroll")                                                            \
  for (int kk = 0; kk < 2; ++kk) {                                             \
    int krow = (base + kk) * 16 + l15;                                         \
    int ch0 = (g ^ (krow & 7)) << 3, ch1 = ((4 + g) ^ (krow & 7)) << 3;        \
    bf16x8 kf0 = *reinterpret_cast<const bf16x8*>(&Kl[btop][krow * 64 + ch0]); \
    sA_[kk] = __builtin_amdgcn_mfma_f32_16x16x32_bf16(kf0, qA0, sA_[kk],0,0,0);\
    sB_[kk] = __builtin_amdgcn_mfma_f32_16x16x32_bf16(kf0, qB0, sB_[kk],0,0,0);\
    sC_[kk] = __builtin_amdgcn_mfma_f32_16x16x32_bf16(kf0, qC0, sC_[kk],0,0,0);\
    sD_[kk] = __builtin_amdgcn_mfma_f32_16x16x32_bf16(kf0, qD0, sD_[kk],0,0,0);\
    bf16x8 kf1 = *reinterpret_cast<const bf16x8*>(&Kl[btop][krow * 64 + ch1]); \
    sA_[kk] = __builtin_amdgcn_mfma_f32_16x16x32_bf16(kf1, qA1, sA_[kk],0,0,0);\
    sB_[kk] = __builtin_amdgcn_mfma_f32_16x16x32_bf16(kf1, qB1, sB_[kk],0,0,0);\
    sC_[kk] = __builtin_amdgcn_mfma_f32_16x16x32_bf16(kf1, qC1, sC_[kk],0,0,0);\
    sD_[kk] = __builtin_amdgcn_mfma_f32_16x16x32_bf16(kf1, qD1, sD_[kk],0,0,0);\
  }                                                                            \
  __builtin_amdgcn_s_setprio(0);

#define PVSLICE(chsel, paA_, paB_, paC_, paD_)                                 \
  __builtin_amdgcn_s_setprio(1);                                               \
  _Pragma("unroll")                                                            \
  for (int nt = 0; nt < 4; ++nt) {                                             \
    int row = nt * 16 + l15;                                                   \
    int ch = (((chsel) + g) ^ (row & 7)) << 3;                                 \
    bf16x8 vf = *reinterpret_cast<const bf16x8*>(&Vl[btop][row * 64 + ch]);    \
    oA[nt] = __builtin_amdgcn_mfma_f32_16x16x32_bf16(paA_, vf, oA[nt],0,0,0);  \
    oB[nt] = __builtin_amdgcn_mfma_f32_16x16x32_bf16(paB_, vf, oB[nt],0,0,0);  \
    oC[nt] = __builtin_amdgcn_mfma_f32_16x16x32_bf16(paC_, vf, oC[nt],0,0,0);  \
    oD[nt] = __builtin_amdgcn_mfma_f32_16x16x32_bf16(paD_, vf, oD[nt],0,0,0);  \
  }                                                                            \
  __builtin_amdgcn_s_setprio(0);

  stage(0, 0);
  stage(1, 1);
  asm volatile("s_waitcnt vmcnt(4)" ::: "memory");
  __builtin_amdgcn_s_barrier();
  asm volatile("" ::: "memory");

  int btop = 0;
  for (int t = 0; t < 16; ++t) {
    if (t < 14) {
      int bnx = btop + 2; if (bnx >= 3) bnx -= 3;
      stage(bnx, t + 2);                       // loads span 2 compute phases
    }

    {  // slice 0: k = 0..31
      floatx4 sA[2], sB[2], sC[2], sD[2];
      #pragma unroll
      for (int kk = 0; kk < 2; ++kk) { sA[kk]=zero; sB[kk]=zero; sC[kk]=zero; sD[kk]=zero; }
      QKSLICE(0, sA, sB, sC, sD);
      bf16x8 paA, paB, paC, paD;
      SOFTSLICE(sA, lrunA, paA);
      SOFTSLICE(sB, lrunB, paB);
      SOFTSLICE(sC, lrunC, paC);
      SOFTSLICE(sD, lrunD, paD);
      PVSLICE(0, paA, paB, paC, paD);
    }
    {  // slice 1: k = 32..63
      floatx4 sA[2], sB[2], sC[2], sD[2];
      #pragma unroll
      for (int kk = 0; kk < 2; ++kk) { sA[kk]=zero; sB[kk]=zero; sC[kk]=zero; sD[kk]=zero; }
      QKSLICE(2, sA, sB, sC, sD);
      bf16x8 paA, paB, paC, paD;
      SOFTSLICE(sA, lrunA, paA);
      SOFTSLICE(sB, lrunB, paB);
      SOFTSLICE(sC, lrunC, paC);
      SOFTSLICE(sD, lrunD, paD);
      PVSLICE(4, paA, paB, paC, paD);
    }

    if (t < 15) {
      if (t < 14) asm volatile("s_waitcnt vmcnt(4)" ::: "memory");
      else        asm volatile("s_waitcnt vmcnt(0)" ::: "memory");
      __builtin_amdgcn_s_barrier();
      asm volatile("" ::: "memory");
    }
    btop = btop + 1 == 3 ? 0 : btop + 1;
  }

  // ---- epilogue ----
  const int b = bh >> 4, h = bh & 15;
  lrunA += __shfl_xor(lrunA, 16); lrunA += __shfl_xor(lrunA, 32);
  lrunB += __shfl_xor(lrunB, 16); lrunB += __shfl_xor(lrunB, 32);
  lrunC += __shfl_xor(lrunC, 16); lrunC += __shfl_xor(lrunC, 32);
  lrunD += __shfl_xor(lrunD, 16); lrunD += __shfl_xor(lrunD, 32);
  float invA = 1.f / lrunA, invB = 1.f / lrunB;
  float invC = 1.f / lrunC, invD = 1.f / lrunD;
  #pragma unroll
  for (int r = 0; r < 4; ++r) {
    float irA = __shfl(invA, slb + r);
    float irB = __shfl(invB, slb + r);
    float irC = __shfl(invC, slb + r);
    float irD = __shfl(invD, slb + r);
    int nA = q0 + wid * 16 + g * 4 + r;
    size_t baseA = ((size_t)(b * 1024) + nA) * 1024 + h * 64;
    size_t baseB = baseA + (size_t)64 * 1024;
    size_t baseC = baseA + (size_t)128 * 1024;
    size_t baseD = baseA + (size_t)192 * 1024;
    #pragma unroll
    for (int nt = 0; nt < 4; ++nt) {
      aout[baseA + nt * 16 + l15] = f2bf(oA[nt][r] * irA);
      aout[baseB + nt * 16 + l15] = f2bf(oB[nt][r] * irB);
      aout[baseC + nt * 16 + l15] = f2bf(oC[nt][r] * irC);
      aout[baseD + nt * 16 + l15] = f2bf(oD[nt][r] * irD);
    }
  }
#undef SOFTSLICE
#undef QKSLICE
#undef PVSLICE
}

// ---------------------------------------------------------------------------
extern "C" void kernel_launch(void* const* d_in, const int* in_sizes, int n_in,
                              void* d_out, int out_size, void* d_ws, size_t ws_size,
                              hipStream_t stream) {
  const float* x      = (const float*)d_in[0];   // [8,1024,1024]
  const float* ropef  = (const float*)d_in[1];   // [1,1024,1,64]
  const float* qkv_w  = (const float*)d_in[2];   // [3072,1024]
  const float* proj_w = (const float*)d_in[3];   // [1024,1024]
  const float* proj_b = (const float*)d_in[4];   // [1024]
  float* out = (float*)d_out;

  char* ws = (char*)d_ws;
  short*  xb  = (short*)(ws + 0);            // 16 MB  x bf16        (contiguous with)
  short*  wqb = (short*)(ws + 16777216);     //  6 MB  qkv_w bf16    (contiguous with)
  short*  wpb = (short*)(ws + 23068672);     //  2 MB  proj_w bf16
  short*  qb  = (short*)(ws + 25165824);     // 16 MB  q [bh][n][d] (RoPE+scale)
  short*  kb  = (short*)(ws + 41943040);     // 16 MB  k [bh][n][d] (RoPE)
  short*  vtb = (short*)(ws + 58720256);     // 16 MB  v^T [bh][d][n]
  short*  aob = (short*)(ws + 75497472);     // 16 MB  attn out bf16 [B][N][C]
  float2* tbl = (float2*)(ws + 92274688);    // 512 KB cos/sin table

  prep_all<<<2304, 256, 0, stream>>>(x, qkv_w, proj_w, xb, ropef, tbl);

  gemm_qkv_k<<<dim3(12, 64), 1024, 98304, stream>>>(xb, wqb, tbl, qb, kb, vtb);
  attn_kernel<<<dim3(128, 4), 256, 0, stream>>>(qb, kb, vtb, aob);
  gemm_proj_k<<<dim3(4, 64), 1024, 98304, stream>>>(aob, wpb, proj_b, out);
}